// Round 9
// baseline (127.383 us; speedup 1.0000x reference)
//
#include <hip/hip_runtime.h>
#include <math.h>

// dims
#define HWHW 2304   // 48*48
#define JD   144    // 12*12
#define LSP  148    // Ls row stride in dwords

typedef __attribute__((ext_vector_type(8))) short short8;
typedef __attribute__((ext_vector_type(4))) float f32x4;
typedef __attribute__((ext_vector_type(2))) float f32x2;

__device__ inline ushort f2bf(float f) {
  uint u = __float_as_uint(f);
  u += 0x7fffu + ((u >> 16) & 1u);   // RNE
  return (ushort)(u >> 16);
}
__device__ inline float bf2f(ushort s) { return __uint_as_float((uint)s << 16); }
__device__ inline uint packbf(float hi, float lo) {   // truncating {hi16(hi),hi16(lo)}
  return __builtin_amdgcn_perm(__float_as_uint(hi), __float_as_uint(lo), 0x07060302);
}

// ws layout (byte offsets)
// kt_bf   [8][144][32] u16   @ 9216    (73728 B)
// vtT_bf  [8][32][160] u16   @ 82944   (81920 B, j=144..159 zeroed)
// outh_bf [2][2304][128] u16 @ 164864  (1179648 B, end 1344512)
// S0g     [8][48][144] f32   @ 1344512 (221184 B)  s0 = f(bg, ix, jj)
// S1g     [8][48][144] f32   @ 1565696 (221184 B)  s1 = f(bg, iy, jj)
// qg      [8][2304][32] u16  @ 1786880 (1179648 B) q-field bf16 (hoisted from attn)

// grid (12 hd, 8 bg), 384 thr = 6 waves. Fused: q=Wq·x via MFMA (wave w owns
// conv input row ry=w) -> depthwise conv -> GELU -> proj -> tanh -> grid coords
// -> bilinear sample -> k/v proj (bf16 out). Emits CPB log1p tables AND the
// bf16 q-field qg (the same values attn's per-block q-tile MFMA produced —
// hoisted here because this kernel already computes the full q field for the
// conv; removes the serial wave-0 q chain from 1152 attn blocks).
__global__ __launch_bounds__(384) void offset_kv_kernel(
    const float* __restrict__ x, const float* __restrict__ wq,
    const float* __restrict__ wdw, const float* __restrict__ bdw,
    const float* __restrict__ wproj, const float* __restrict__ wk,
    const float* __restrict__ wv,
    ushort* __restrict__ ktb, ushort* __restrict__ vtb,
    float* __restrict__ S0g, float* __restrict__ S1g,
    ushort* __restrict__ qg) {
  __shared__ float qs[288][33];      // [ry*48+col][c], +1 pad
  __shared__ float wdws[36][32];     // [k][c]
  __shared__ float wkl[32][33], wvl[32][33];   // [d][c]
  __shared__ float kvs[32][13];      // [c][j] (+pad)
  __shared__ float spx[12], spy[12];
  __shared__ float spn0[12], spn1[12];   // normalized grid coords (vn values)
  int hd = blockIdx.x, bg = blockIdx.y, b = bg >> 2, g = bg & 3;
  int t = threadIdx.x;
  int w = t >> 6, lane = t & 63, lam = lane & 15, quad = lane >> 4;

  // ---- q-tile via MFMA: wave w computes conv-input row ry=w (hy=hd*4-1+w) ----
  {
    int hy = hd * 4 - 1 + w;
    if (hy >= 0 && hy < 48) {
      const float* wqg = wq + (g * 32) * 32;
      float4 wa = *(const float4*)(wqg + lam * 32 + quad * 8);
      float4 wb = *(const float4*)(wqg + lam * 32 + quad * 8 + 4);
      float4 wc = *(const float4*)(wqg + (16 + lam) * 32 + quad * 8);
      float4 wd = *(const float4*)(wqg + (16 + lam) * 32 + quad * 8 + 4);
      union { uint u[4]; short8 s8; } bf0, bf1;
      bf0.u[0] = packbf(wa.y, wa.x); bf0.u[1] = packbf(wa.w, wa.z);
      bf0.u[2] = packbf(wb.y, wb.x); bf0.u[3] = packbf(wb.w, wb.z);
      bf1.u[0] = packbf(wc.y, wc.x); bf1.u[1] = packbf(wc.w, wc.z);
      bf1.u[2] = packbf(wd.y, wd.x); bf1.u[3] = packbf(wd.w, wd.z);
      const float* xg = x + (b * 128 + g * 32) * HWHW + hy * 48;
#pragma unroll
      for (int tt = 0; tt < 3; ++tt) {
        int col = tt * 16 + lam;
        union { uint u[4]; short8 s8; } xa;
#pragma unroll
        for (int j = 0; j < 4; ++j) {
          float x0 = xg[(quad * 8 + 2 * j) * HWHW + col];
          float x1 = xg[(quad * 8 + 2 * j + 1) * HWHW + col];
          xa.u[j] = packbf(x1, x0);
        }
        f32x4 z = {0.f, 0.f, 0.f, 0.f};
        f32x4 d0 = __builtin_amdgcn_mfma_f32_16x16x32_bf16(xa.s8, bf0.s8, z, 0, 0, 0);
        f32x4 d1 = __builtin_amdgcn_mfma_f32_16x16x32_bf16(xa.s8, bf1.s8, z, 0, 0, 0);
        int p = w * 48 + tt * 16 + quad * 4;
#pragma unroll
        for (int r = 0; r < 4; ++r) {
          qs[p + r][lam] = d0[r];
          qs[p + r][16 + lam] = d1[r];
        }
      }
    } else {
#pragma unroll
      for (int tt = 0; tt < 3; ++tt) {
        int p = w * 48 + tt * 16 + quad * 4;
#pragma unroll
        for (int r = 0; r < 4; ++r) {
          qs[p + r][lam] = 0.f;
          qs[p + r][16 + lam] = 0.f;
        }
      }
    }
  }
  for (int u = t; u < 1152; u += 384) wdws[u >> 5][u & 31] = wdw[(u & 31) * 36 + (u >> 5)];
  for (int u = t; u < 1024; u += 384) {
    int d = u >> 5, c = u & 31;
    wkl[d][c] = wk[g * 1024 + u];
    wvl[d][c] = wv[g * 1024 + u];
  }
  __syncthreads();
  // ---- export q-field to global bf16 (values == attn's old q-tile output;
  //      overlapping rows across hd-blocks write identical values) ----
  {
    for (int u = t; u < 9216; u += 384) {
      int pos = u >> 5, ch = u & 31;
      int wrow = pos / 48;
      int hy = hd * 4 - 1 + wrow;
      if (hy >= 0 && hy < 48)
        qg[((bg * 2304 + hy * 48 + (pos - wrow * 48)) << 5) + ch] = f2bf(qs[pos][ch]);
    }
  }
  {
    int wd = t >> 5, c = t & 31;
    float s = 0.f;
#pragma unroll
    for (int ky = 0; ky < 6; ++ky) {
#pragma unroll
      for (int kx = 0; kx < 6; ++kx) {
        int wx = wd * 4 - 1 + kx;
        if (wx >= 0 && wx < 48)
          s += wdws[ky * 6 + kx][c] * qs[ky * 48 + wx][c];
      }
    }
    s += bdw[c];
    s = 0.5f * s * (1.f + erff(s * 0.70710678118654752f));  // exact GELU
    float g0 = wproj[c] * s;
    float g1 = wproj[32 + c] * s;
#pragma unroll
    for (int k = 16; k >= 1; k >>= 1) {
      g0 += __shfl_xor(g0, k, 64);
      g1 += __shfl_xor(g1, k, 64);
    }
    if (c == 0) {
      float off0 = tanhf(g0) * 4.f;
      float off1 = tanhf(g1) * 4.f;
      float n0 = 2.f * ((float)wd + off0) / 11.f - 1.f;
      float n1 = 2.f * ((float)hd + off1) / 11.f - 1.f;
      spn0[wd] = n0;
      spn1[wd] = n1;
      spx[wd] = ((n0 + 1.f) * 48.f - 1.f) * 0.5f;
      spy[wd] = ((n1 + 1.f) * 48.f - 1.f) * 0.5f;
    }
  }
  __syncthreads();
  {
    int j = t >> 5, c = t & 31;
    float fx = spx[j], fy = spy[j];
    float x0 = floorf(fx), y0 = floorf(fy);
    float wx = fx - x0, wy = fy - y0;
    int xi = (int)x0, yi = (int)y0;
    const float* xp = x + (b * 128 + g * 32 + c) * HWHW;
    float v00 = 0.f, v10 = 0.f, v01 = 0.f, v11 = 0.f;
    bool okx0 = (xi >= 0) & (xi < 48), okx1 = (xi + 1 >= 0) & (xi + 1 < 48);
    if (yi >= 0 && yi < 48) {
      if (okx0) v00 = xp[yi * 48 + xi];
      if (okx1) v10 = xp[yi * 48 + xi + 1];
    }
    if (yi + 1 >= 0 && yi + 1 < 48) {
      if (okx0) v01 = xp[(yi + 1) * 48 + xi];
      if (okx1) v11 = xp[(yi + 1) * 48 + xi + 1];
    }
    kvs[c][j] = v00 * (1.f - wx) * (1.f - wy) + v10 * wx * (1.f - wy)
              + v01 * (1.f - wx) * wy + v11 * wx * wy;
  }
  // ---- CPB log1p tables: this block owns jj = hd*12 + wd, wd in [0,12) ----
  {
#pragma unroll
    for (int it = 0; it < 3; ++it) {
      int u = t + it * 384;
      int tab = u >= 576;
      int idx = tab ? u - 576 : u;
      int ii = idx / 12, wd = idx - ii * 12;     // ii = ix (tab 0) or iy (tab 1)
      float qn = (float)ii * (2.f / 47.f) - 1.f;
      float nv = tab ? spn1[wd] : spn0[wd];
      float p = qn - nv;
      float sres = copysignf(__logf(1.f + fabsf(p)), p);
      float* dst = tab ? S1g : S0g;
      dst[bg * 6912 + ii * 144 + hd * 12 + wd] = sres;
    }
  }
  __syncthreads();
  {
    int j = t >> 5, d = t & 31;
    float ak = 0.f, av = 0.f;
#pragma unroll
    for (int c = 0; c < 32; ++c) {
      float val = kvs[c][j];
      ak += wkl[d][c] * val;
      av += wvl[d][c] * val;
    }
    int jg = hd * 12 + j;
    ktb[bg * 4608 + jg * 32 + d] = f2bf(ak);
    vtb[bg * 5120 + d * 160 + jg] = f2bf(av);
  }
  if (hd == 0) {   // zero the v K-pad for this bg (j = 144..159)
    for (int u = t; u < 512; u += 384)
      vtb[bg * 5120 + (u >> 4) * 160 + 144 + (u & 15)] = 0;
  }
}

// Fused attention: block = (bg, 16 q-rows), 512 thr = 8 waves, (512,4).
// vs R8: the per-block q-tile MFMA (serial wave-0 chain: strided x loads +
// wq loads + 2 MFMA) is GONE — qbf is staged from the precomputed global
// qg with one 1 KB coalesced copy. x/wq args dropped.
__global__ __launch_bounds__(512, 4) void attn_fused_kernel(
    const ushort* __restrict__ qg,
    const ushort* __restrict__ ktb, const ushort* __restrict__ vtb,
    const float* __restrict__ S0g, const float* __restrict__ S1g,
    const float* __restrict__ w0, const float* __restrict__ b0,
    const float* __restrict__ w1, const float* __restrict__ b1,
    const float* __restrict__ w2,
    ushort* __restrict__ outh) {
  __shared__ __align__(16) char smem[30528];
  float* Ls = (float*)smem;                    // [16][LSP] fp32; P bf16 at dwords 64..143
  float* st0f = (float*)(smem + 9472);         // [16*144] s0 per (row,jj)
  float* st1f = (float*)(smem + 18688);        // [144]    s1 per jj (iy fixed)
  ushort* qbf = (ushort*)(smem + 19264);       // [16][32] bf16
  float* bvs = (float*)(smem + 20288);         // [5][512] per-thread biasv scratch

  int bg = blockIdx.y, b = bg >> 2, g = bg & 3;
  int i0 = blockIdx.x * 16;
  int t = threadIdx.x;
  int w = t >> 6, lane = t & 63;
  int lam = lane & 15, quad = lane >> 4;

  // ---- prefetch this wave's K-fragment(s) (consumed in P1 after B0) ----
  short8 bk0, bk8;
  {
    const ushort* kb = ktb + bg * 4608;
    bk0 = *(const short8*)(kb + (w * 16 + lam) * 32 + quad * 8);
    if (w == 0) bk8 = *(const short8*)(kb + (128 + lam) * 32 + quad * 8);
  }

  // ---- stage q-tile (1 KB coalesced; rows i0..i0+15 contiguous in qg) ----
  if (t < 256)
    ((uint*)qbf)[t] = ((const uint*)(qg + ((long)(bg * 2304 + i0) << 5)))[t];

  // ---- stage log1p tables (coalesced, no math) ----
  {
    int iy = i0 / 48;
    int ix0 = i0 - iy * 48;
    const float* S0p = S0g + bg * 6912 + ix0 * 144;
#pragma unroll
    for (int it = 0; it < 4; ++it) st0f[t + it * 512] = S0p[t + it * 512];
    if (t < 256) st0f[t + 2048] = S0p[t + 2048];
    if (t < JD) st1f[t] = S1g[bg * 6912 + iy * 144 + t];
  }

  // ---- per-lane resident weights (all waves; needed for P2) ----
  f32x2 w00r2[4], w01r2[4], b0r2[4];
#pragma unroll
  for (int j = 0; j < 4; ++j) {
    int k = quad * 8 + 2 * j;
    w00r2[j] = (f32x2){w0[k], w0[k + 1]};
    w01r2[j] = (f32x2){w0[32 + k], w0[32 + k + 1]};
    b0r2[j]  = (f32x2){b0[k], b0[k + 1]};
  }
  short8 w1f0, w1f1;   // W1^T A-frags (m=n-out, k=c-in), two 16-row tiles
#pragma unroll
  for (int j = 0; j < 8; ++j) {
    int k = quad * 8 + j;
    w1f0[j] = (short)f2bf(w1[k * 32 + lam]);
    w1f1[j] = (short)f2bf(w1[k * 32 + 16 + lam]);
  }
  f32x4 zA, zB;       // b1 folded into C-init (n = quad*4+r / 16+quad*4+r)
  f32x2 w2A01, w2A23, w2B01, w2B23;
#pragma unroll
  for (int r = 0; r < 4; ++r) {
    zA[r] = b1[quad * 4 + r];
    zB[r] = b1[16 + quad * 4 + r];
  }
  w2A01 = (f32x2){w2[quad * 4], w2[quad * 4 + 1]};
  w2A23 = (f32x2){w2[quad * 4 + 2], w2[quad * 4 + 3]};
  w2B01 = (f32x2){w2[16 + quad * 4], w2[16 + quad * 4 + 1]};
  w2B23 = (f32x2){w2[16 + quad * 4 + 2], w2[16 + quad * 4 + 3]};
  // b2 dropped: scalar shift of all logits, softmax-invariant (exact).

  __syncthreads();   // B0: qbf + st ready

  // ---- P1: sim = q·kT (scaled), bk prefetched; then P2-compute in the SAME
  //      phase (MLP chains are independent of sim -> P1 latency hides) ----
  const float scale = 0.17677669529663687f;   // 32^-0.5
  {
    short8 aq = *(const short8*)(qbf + lam * 32 + quad * 8);
    f32x4 z = {0.f, 0.f, 0.f, 0.f};
    f32x4 acc = __builtin_amdgcn_mfma_f32_16x16x32_bf16(aq, bk0, z, 0, 0, 0);
#pragma unroll
    for (int r = 0; r < 4; ++r)
      Ls[(quad * 4 + r) * LSP + w * 16 + lam] = acc[r] * scale;
    if (w == 0) {
      f32x4 acc8 = __builtin_amdgcn_mfma_f32_16x16x32_bf16(aq, bk8, z, 0, 0, 0);
#pragma unroll
      for (int r = 0; r < 4; ++r)
        Ls[(quad * 4 + r) * LSP + 128 + lam] = acc8[r] * scale;
    }
  }

  // ---- P2-compute: CPB bias MLP -> bvs (no sim dependency, no barrier) ----
  const f32x2 zero2 = {0.f, 0.f};
  int wr = w & 3;
  int pbase = wr * 576;
  int sA = (w < 4) ? 0 : 4;
  int sB = (w < 4) ? 4 : 9;
#pragma unroll 1
  for (int s = sA; s < sB; ++s) {
    float bm[4];
#pragma unroll
    for (int mt = 0; mt < 4; ++mt) {
      int Pm = pbase + s * 64 + mt * 16 + lam;
      float s0 = st0f[Pm];                     // broadcast across quads
      int iim = Pm / 144;
      float s1 = st1f[Pm - iim * 144];
      f32x2 s0v = {s0, s0}, s1v = {s1, s1};
      union { uint u[4]; short8 s8; } cvt;
#pragma unroll
      for (int j = 0; j < 4; ++j) {
        f32x2 hv = __builtin_elementwise_max(
            __builtin_elementwise_fma(s0v, w00r2[j],
                __builtin_elementwise_fma(s1v, w01r2[j], b0r2[j])), zero2);
        cvt.u[j] = packbf(hv[1], hv[0]);
      }
      f32x4 dA = __builtin_amdgcn_mfma_f32_16x16x32_bf16(w1f0, cvt.s8, zA, 0, 0, 0);
      f32x4 dB = __builtin_amdgcn_mfma_f32_16x16x32_bf16(w1f1, cvt.s8, zB, 0, 0, 0);
      f32x2 a01 = __builtin_elementwise_max((f32x2){dA[0], dA[1]}, zero2);
      f32x2 a23 = __builtin_elementwise_max((f32x2){dA[2], dA[3]}, zero2);
      f32x2 c01 = __builtin_elementwise_max((f32x2){dB[0], dB[1]}, zero2);
      f32x2 c23 = __builtin_elementwise_max((f32x2){dB[2], dB[3]}, zero2);
      f32x2 av = __builtin_elementwise_fma(a01, w2A01,
                 __builtin_elementwise_fma(a23, w2A23,
                 __builtin_elementwise_fma(c01, w2B01,
                 __builtin_elementwise_fma(c23, w2B23, zero2))));
      float acc = av[0] + av[1];
      acc += __shfl_xor(acc, 16, 64);
      acc += __shfl_xor(acc, 32, 64);
      bm[mt] = acc;
    }
    float biasv = (quad == 0 ? bm[0] : quad == 1 ? bm[1] : quad == 2 ? bm[2] : bm[3]);
    bvs[(s - sA) * 512 + t] = biasv;           // per-thread slot
  }
  __syncthreads();   // B2: sim in Ls complete, bvs complete

  // ---- bias-add (tiny): Ls += bvs; disjoint (ii,jj) per lane per s ----
#pragma unroll 1
  for (int s = sA; s < sB; ++s) {
    int P = s * 64 + lane;
    int ii = P / 144, jj = P - ii * 144;
    Ls[(wr * 4 + ii) * LSP + jj] += bvs[(s - sA) * 512 + t];
  }
  __syncthreads();   // B3

  // ---- prefetch v-frags for P4 (waves 0,1); latency hides under P3 ----
  short8 vf[5];
  if (w < 2) {
    const ushort* vb = vtb + bg * 5120 + (w * 16 + lam) * 160;
#pragma unroll
    for (int kb = 0; kb < 5; ++kb)
      vf[kb] = *(const short8*)(vb + kb * 32 + quad * 8);
  }

  // ---- P3: softmax on waves 0-3 (quad = row, 16 lanes/row) ----
  if (w < 4) {
    int row = w * 4 + quad;
    float* Lp = Ls + row * LSP;
    float lv[9];
#pragma unroll
    for (int k = 0; k < 9; ++k) lv[k] = Lp[lam + 16 * k];
    float m = lv[0];
#pragma unroll
    for (int k = 1; k < 9; ++k) m = fmaxf(m, lv[k]);
#pragma unroll
    for (int k = 8; k >= 1; k >>= 1) m = fmaxf(m, __shfl_xor(m, k, 64));
    float e[9], sum = 0.f;
#pragma unroll
    for (int k = 0; k < 9; ++k) { e[k] = __expf(lv[k] - m); sum += e[k]; }
#pragma unroll
    for (int k = 8; k >= 1; k >>= 1) sum += __shfl_xor(sum, k, 64);
    float inv = 1.f / sum;
    ushort* pb = (ushort*)(Lp + 64);
#pragma unroll
    for (int k = 0; k < 9; ++k) pb[lam + 16 * k] = f2bf(e[k] * inv);
    pb[144 + lam] = 0;   // K-pad for P4
  }
  __syncthreads();   // B4

  // ---- P4: O = P·v (K=160, zero-padded); waves 0,1 take the 2 col-halves ----
  if (w < 2) {
    f32x4 o = {0.f, 0.f, 0.f, 0.f};
    const ushort* pb = (const ushort*)(Ls + lam * LSP + 64);
#pragma unroll
    for (int kb = 0; kb < 5; ++kb) {
      short8 ap = *(const short8*)(pb + kb * 32 + quad * 8);
      o = __builtin_amdgcn_mfma_f32_16x16x32_bf16(ap, vf[kb], o, 0, 0, 0);
    }
#pragma unroll
    for (int r = 0; r < 4; ++r) {
      int ig = i0 + quad * 4 + r;
      outh[((long)b * HWHW + ig) * 128 + g * 32 + w * 16 + lam] = f2bf(o[r]);
    }
  }
}

// grid (144 hw-chunks, 2 b, 2 oc-halves), 256 thr = 4 waves; wave owns 16 oc.
// MFMA out-proj, zero LDS: A-frags straight from bf16 outh; B-frags from fp32
// wo with inline v_perm pack.
__global__ __launch_bounds__(256) void out_kernel(
    const ushort* __restrict__ outh, const float* __restrict__ wo,
    const float* __restrict__ bo, const float* __restrict__ x,
    const float* __restrict__ gamma, float* __restrict__ out) {
  int b = blockIdx.y;
  int hw0 = blockIdx.x * 16;
  int oc0 = blockIdx.z * 64;
  int t = threadIdx.x;
  int w = t >> 6, lane = t & 63, lam = lane & 15, quad = lane >> 4;
  const ushort* abase = outh + ((long)b * HWHW + hw0 + lam) * 128 + quad * 8;
  const float* wb0 = wo + (oc0 + w * 16 + lam) * 128 + quad * 8;
  f32x4 acc0 = {0.f, 0.f, 0.f, 0.f};
#pragma unroll
  for (int ks = 0; ks < 4; ++ks) {
    short8 a = *(const short8*)(abase + ks * 32);
    float4 wa = *(const float4*)(wb0 + ks * 32);
    float4 wb = *(const float4*)(wb0 + ks * 32 + 4);
    union { uint u[4]; short8 s8; } p0;
    p0.u[0] = packbf(wa.y, wa.x); p0.u[1] = packbf(wa.w, wa.z);
    p0.u[2] = packbf(wb.y, wb.x); p0.u[3] = packbf(wb.w, wb.z);
    acc0 = __builtin_amdgcn_mfma_f32_16x16x32_bf16(a, p0.s8, acc0, 0, 0, 0);
  }
  float gm = gamma[0];
  float* out0 = out;
  float* out1 = out + 2 * 128 * HWHW;
  {
    int oc = oc0 + w * 16 + lam;
    float bv = bo[oc];
    long base = ((long)(b * 128 + oc)) * HWHW + hw0 + quad * 4;
    float4 xv = *(const float4*)(x + base);
    float4 a1, a0;
    a1.x = acc0[0] + bv; a1.y = acc0[1] + bv; a1.z = acc0[2] + bv; a1.w = acc0[3] + bv;
    a0.x = fmaf(gm, a1.x, xv.x); a0.y = fmaf(gm, a1.y, xv.y);
    a0.z = fmaf(gm, a1.z, xv.z); a0.w = fmaf(gm, a1.w, xv.w);
    *(float4*)(out1 + base) = a1;
    *(float4*)(out0 + base) = a0;
  }
}

extern "C" void kernel_launch(void* const* d_in, const int* in_sizes, int n_in,
                              void* d_out, int out_size, void* d_ws, size_t ws_size,
                              hipStream_t stream) {
  const float* x     = (const float*)d_in[0];
  const float* gamma = (const float*)d_in[1];
  const float* wq    = (const float*)d_in[2];
  const float* wk    = (const float*)d_in[3];
  const float* wv    = (const float*)d_in[4];
  const float* wo    = (const float*)d_in[5];
  const float* bo    = (const float*)d_in[6];
  const float* wdw   = (const float*)d_in[7];
  const float* bdw   = (const float*)d_in[8];
  const float* wproj = (const float*)d_in[9];
  const float* cw0   = (const float*)d_in[10];
  const float* cb0   = (const float*)d_in[11];
  const float* cw1   = (const float*)d_in[12];
  const float* cb1   = (const float*)d_in[13];
  const float* cw2   = (const float*)d_in[14];
  char* wsb = (char*)d_ws;
  ushort* ktb = (ushort*)(wsb + 9216);
  ushort* vtb = (ushort*)(wsb + 82944);
  ushort* outh = (ushort*)(wsb + 164864);
  float* S0g  = (float*)(wsb + 1344512);
  float* S1g  = (float*)(wsb + 1565696);
  ushort* qg  = (ushort*)(wsb + 1786880);
  float* out  = (float*)d_out;

  offset_kv_kernel<<<dim3(12, 8), 384, 0, stream>>>(x, wq, wdw, bdw, wproj, wk, wv,
                                                    ktb, vtb, S0g, S1g, qg);
  attn_fused_kernel<<<dim3(144, 8), 512, 0, stream>>>(qg, ktb, vtb, S0g, S1g,
                                                      cw0, cb0, cw1, cb1, cw2, outh);
  out_kernel<<<dim3(144, 2, 2), 256, 0, stream>>>(outh, wo, bo, x, gamma, out);
}

// Round 11
// 125.590 us; speedup vs baseline: 1.0143x; 1.0143x over previous
//
#include <hip/hip_runtime.h>
#include <math.h>

// dims
#define HWHW 2304   // 48*48
#define JD   144    // 12*12
#define LSP  148    // Ls row stride in dwords

typedef __attribute__((ext_vector_type(8))) short short8;
typedef __attribute__((ext_vector_type(4))) float f32x4;
typedef __attribute__((ext_vector_type(2))) float f32x2;

__device__ inline ushort f2bf(float f) {
  uint u = __float_as_uint(f);
  u += 0x7fffu + ((u >> 16) & 1u);   // RNE
  return (ushort)(u >> 16);
}
__device__ inline float bf2f(ushort s) { return __uint_as_float((uint)s << 16); }
__device__ inline uint packbf(float hi, float lo) {   // truncating {hi16(hi),hi16(lo)}
  return __builtin_amdgcn_perm(__float_as_uint(hi), __float_as_uint(lo), 0x07060302);
}

// ws layout (byte offsets)
// kt_bf   [8][144][32] u16   @ 9216    (73728 B)
// vtT_bf  [8][32][160] u16   @ 82944   (81920 B, j=144..159 zeroed)
// outh_bf [2][2304][128] u16 @ 164864  (1179648 B, end 1344512)
// S0g     [8][48][144] f32   @ 1344512 (221184 B)  s0 = f(bg, ix, jj)
// S1g     [8][48][144] f32   @ 1565696 (221184 B)  s1 = f(bg, iy, jj)

// grid (12 hd, 8 bg), 384 thr = 6 waves. Fused: q=Wq·x via MFMA (wave w owns
// conv input row ry=w) -> depthwise conv -> GELU -> proj -> tanh -> grid coords
// -> bilinear sample -> k/v proj (bf16 out). Also emits the CPB log1p tables.
__global__ __launch_bounds__(384) void offset_kv_kernel(
    const float* __restrict__ x, const float* __restrict__ wq,
    const float* __restrict__ wdw, const float* __restrict__ bdw,
    const float* __restrict__ wproj, const float* __restrict__ wk,
    const float* __restrict__ wv,
    ushort* __restrict__ ktb, ushort* __restrict__ vtb,
    float* __restrict__ S0g, float* __restrict__ S1g) {
  __shared__ float qs[288][33];      // [ry*48+col][c], +1 pad
  __shared__ float wdws[36][32];     // [k][c]
  __shared__ float wkl[32][33], wvl[32][33];   // [d][c]
  __shared__ float kvs[32][13];      // [c][j] (+pad)
  __shared__ float spx[12], spy[12];
  __shared__ float spn0[12], spn1[12];   // normalized grid coords (vn values)
  int hd = blockIdx.x, bg = blockIdx.y, b = bg >> 2, g = bg & 3;
  int t = threadIdx.x;
  int w = t >> 6, lane = t & 63, lam = lane & 15, quad = lane >> 4;

  // ---- q-tile via MFMA: wave w computes conv-input row ry=w (hy=hd*4-1+w) ----
  {
    int hy = hd * 4 - 1 + w;
    if (hy >= 0 && hy < 48) {
      const float* wqg = wq + (g * 32) * 32;
      float4 wa = *(const float4*)(wqg + lam * 32 + quad * 8);
      float4 wb = *(const float4*)(wqg + lam * 32 + quad * 8 + 4);
      float4 wc = *(const float4*)(wqg + (16 + lam) * 32 + quad * 8);
      float4 wd = *(const float4*)(wqg + (16 + lam) * 32 + quad * 8 + 4);
      union { uint u[4]; short8 s8; } bf0, bf1;
      bf0.u[0] = packbf(wa.y, wa.x); bf0.u[1] = packbf(wa.w, wa.z);
      bf0.u[2] = packbf(wb.y, wb.x); bf0.u[3] = packbf(wb.w, wb.z);
      bf1.u[0] = packbf(wc.y, wc.x); bf1.u[1] = packbf(wc.w, wc.z);
      bf1.u[2] = packbf(wd.y, wd.x); bf1.u[3] = packbf(wd.w, wd.z);
      const float* xg = x + (b * 128 + g * 32) * HWHW + hy * 48;
#pragma unroll
      for (int tt = 0; tt < 3; ++tt) {
        int col = tt * 16 + lam;
        union { uint u[4]; short8 s8; } xa;
#pragma unroll
        for (int j = 0; j < 4; ++j) {
          float x0 = xg[(quad * 8 + 2 * j) * HWHW + col];
          float x1 = xg[(quad * 8 + 2 * j + 1) * HWHW + col];
          xa.u[j] = packbf(x1, x0);
        }
        f32x4 z = {0.f, 0.f, 0.f, 0.f};
        f32x4 d0 = __builtin_amdgcn_mfma_f32_16x16x32_bf16(xa.s8, bf0.s8, z, 0, 0, 0);
        f32x4 d1 = __builtin_amdgcn_mfma_f32_16x16x32_bf16(xa.s8, bf1.s8, z, 0, 0, 0);
        int p = w * 48 + tt * 16 + quad * 4;
#pragma unroll
        for (int r = 0; r < 4; ++r) {
          qs[p + r][lam] = d0[r];
          qs[p + r][16 + lam] = d1[r];
        }
      }
    } else {
#pragma unroll
      for (int tt = 0; tt < 3; ++tt) {
        int p = w * 48 + tt * 16 + quad * 4;
#pragma unroll
        for (int r = 0; r < 4; ++r) {
          qs[p + r][lam] = 0.f;
          qs[p + r][16 + lam] = 0.f;
        }
      }
    }
  }
  for (int u = t; u < 1152; u += 384) wdws[u >> 5][u & 31] = wdw[(u & 31) * 36 + (u >> 5)];
  for (int u = t; u < 1024; u += 384) {
    int d = u >> 5, c = u & 31;
    wkl[d][c] = wk[g * 1024 + u];
    wvl[d][c] = wv[g * 1024 + u];
  }
  __syncthreads();
  {
    int wd = t >> 5, c = t & 31;
    float s = 0.f;
#pragma unroll
    for (int ky = 0; ky < 6; ++ky) {
#pragma unroll
      for (int kx = 0; kx < 6; ++kx) {
        int wx = wd * 4 - 1 + kx;
        if (wx >= 0 && wx < 48)
          s += wdws[ky * 6 + kx][c] * qs[ky * 48 + wx][c];
      }
    }
    s += bdw[c];
    s = 0.5f * s * (1.f + erff(s * 0.70710678118654752f));  // exact GELU
    float g0 = wproj[c] * s;
    float g1 = wproj[32 + c] * s;
#pragma unroll
    for (int k = 16; k >= 1; k >>= 1) {
      g0 += __shfl_xor(g0, k, 64);
      g1 += __shfl_xor(g1, k, 64);
    }
    if (c == 0) {
      float off0 = tanhf(g0) * 4.f;
      float off1 = tanhf(g1) * 4.f;
      float n0 = 2.f * ((float)wd + off0) / 11.f - 1.f;
      float n1 = 2.f * ((float)hd + off1) / 11.f - 1.f;
      spn0[wd] = n0;
      spn1[wd] = n1;
      spx[wd] = ((n0 + 1.f) * 48.f - 1.f) * 0.5f;
      spy[wd] = ((n1 + 1.f) * 48.f - 1.f) * 0.5f;
    }
  }
  __syncthreads();
  {
    int j = t >> 5, c = t & 31;
    float fx = spx[j], fy = spy[j];
    float x0 = floorf(fx), y0 = floorf(fy);
    float wx = fx - x0, wy = fy - y0;
    int xi = (int)x0, yi = (int)y0;
    const float* xp = x + (b * 128 + g * 32 + c) * HWHW;
    float v00 = 0.f, v10 = 0.f, v01 = 0.f, v11 = 0.f;
    bool okx0 = (xi >= 0) & (xi < 48), okx1 = (xi + 1 >= 0) & (xi + 1 < 48);
    if (yi >= 0 && yi < 48) {
      if (okx0) v00 = xp[yi * 48 + xi];
      if (okx1) v10 = xp[yi * 48 + xi + 1];
    }
    if (yi + 1 >= 0 && yi + 1 < 48) {
      if (okx0) v01 = xp[(yi + 1) * 48 + xi];
      if (okx1) v11 = xp[(yi + 1) * 48 + xi + 1];
    }
    kvs[c][j] = v00 * (1.f - wx) * (1.f - wy) + v10 * wx * (1.f - wy)
              + v01 * (1.f - wx) * wy + v11 * wx * wy;
  }
  // ---- CPB log1p tables: this block owns jj = hd*12 + wd, wd in [0,12) ----
  {
#pragma unroll
    for (int it = 0; it < 3; ++it) {
      int u = t + it * 384;
      int tab = u >= 576;
      int idx = tab ? u - 576 : u;
      int ii = idx / 12, wd = idx - ii * 12;     // ii = ix (tab 0) or iy (tab 1)
      float qn = (float)ii * (2.f / 47.f) - 1.f;
      float nv = tab ? spn1[wd] : spn0[wd];
      float p = qn - nv;
      float sres = copysignf(__logf(1.f + fabsf(p)), p);
      float* dst = tab ? S1g : S0g;
      dst[bg * 6912 + ii * 144 + hd * 12 + wd] = sres;
    }
  }
  __syncthreads();
  {
    int j = t >> 5, d = t & 31;
    float ak = 0.f, av = 0.f;
#pragma unroll
    for (int c = 0; c < 32; ++c) {
      float val = kvs[c][j];
      ak += wkl[d][c] * val;
      av += wvl[d][c] * val;
    }
    int jg = hd * 12 + j;
    ktb[bg * 4608 + jg * 32 + d] = f2bf(ak);
    vtb[bg * 5120 + d * 160 + jg] = f2bf(av);
  }
  if (hd == 0) {   // zero the v K-pad for this bg (j = 144..159)
    for (int u = t; u < 512; u += 384)
      vtb[bg * 5120 + (u >> 4) * 160 + 144 + (u & 15)] = 0;
  }
}

// Fused attention: block = (bg, 16 q-rows), 512 thr = 8 waves, (512,4).
// vs R8: (1) B3 ELIMINATED — each P3 wave w (<4) owns the bias-add for its
// own rows (bvs partials from waves w and w+4 are complete at B2, and no
// other wave reads those Ls rows before B4), so add+softmax run back-to-back;
// (2) the jt=8 P1 tile moves from wave 0 (which also builds the q-tile) to
// wave 7 — balances the longest prologue chain. 3 barriers total.
__global__ __launch_bounds__(512, 4) void attn_fused_kernel(
    const float* __restrict__ x, const float* __restrict__ wq,
    const ushort* __restrict__ ktb, const ushort* __restrict__ vtb,
    const float* __restrict__ S0g, const float* __restrict__ S1g,
    const float* __restrict__ w0, const float* __restrict__ b0,
    const float* __restrict__ w1, const float* __restrict__ b1,
    const float* __restrict__ w2,
    ushort* __restrict__ outh) {
  __shared__ __align__(16) char smem[30528];
  float* Ls = (float*)smem;                    // [16][LSP] fp32; P bf16 at dwords 64..143
  float* st0f = (float*)(smem + 9472);         // [16*144] s0 per (row,jj)
  float* st1f = (float*)(smem + 18688);        // [144]    s1 per jj (iy fixed)
  ushort* qbf = (ushort*)(smem + 19264);       // [16][32] bf16
  float* bvs = (float*)(smem + 20288);         // [5][512] per-thread biasv scratch

  int bg = blockIdx.y, b = bg >> 2, g = bg & 3;
  int i0 = blockIdx.x * 16;
  int t = threadIdx.x;
  int w = t >> 6, lane = t & 63;
  int lam = lane & 15, quad = lane >> 4;

  // ---- prefetch this wave's K-fragment(s) (consumed in P1 after B0) ----
  short8 bk0, bk8;
  {
    const ushort* kb = ktb + bg * 4608;
    bk0 = *(const short8*)(kb + (w * 16 + lam) * 32 + quad * 8);
    if (w == 7) bk8 = *(const short8*)(kb + (128 + lam) * 32 + quad * 8);
  }

  // ---- stage log1p tables (coalesced, no math) ----
  {
    int iy = i0 / 48;
    int ix0 = i0 - iy * 48;
    const float* S0p = S0g + bg * 6912 + ix0 * 144;
#pragma unroll
    for (int it = 0; it < 4; ++it) st0f[t + it * 512] = S0p[t + it * 512];
    if (t < 256) st0f[t + 2048] = S0p[t + 2048];
    if (t < JD) st1f[t] = S1g[bg * 6912 + iy * 144 + t];
  }

  // ---- q-tile via MFMA (wave 0 only): D = X[16r][32c]·Wq^T -> LDS ----
  if (w == 0) {
    const float* wqg = wq + (g * 32) * 32;
    float4 wa = *(const float4*)(wqg + lam * 32 + quad * 8);
    float4 wb = *(const float4*)(wqg + lam * 32 + quad * 8 + 4);
    float4 wc = *(const float4*)(wqg + (16 + lam) * 32 + quad * 8);
    float4 wd = *(const float4*)(wqg + (16 + lam) * 32 + quad * 8 + 4);
    union { uint u[4]; short8 s8; } bf0, bf1, xa;
    bf0.u[0] = packbf(wa.y, wa.x); bf0.u[1] = packbf(wa.w, wa.z);
    bf0.u[2] = packbf(wb.y, wb.x); bf0.u[3] = packbf(wb.w, wb.z);
    bf1.u[0] = packbf(wc.y, wc.x); bf1.u[1] = packbf(wc.w, wc.z);
    bf1.u[2] = packbf(wd.y, wd.x); bf1.u[3] = packbf(wd.w, wd.z);
    const float* xg = x + (b * 128 + g * 32) * HWHW + i0;
#pragma unroll
    for (int j = 0; j < 4; ++j) {
      float x0 = xg[(quad * 8 + 2 * j) * HWHW + lam];
      float x1 = xg[(quad * 8 + 2 * j + 1) * HWHW + lam];
      xa.u[j] = packbf(x1, x0);
    }
    f32x4 z = {0.f, 0.f, 0.f, 0.f};
    f32x4 d0 = __builtin_amdgcn_mfma_f32_16x16x32_bf16(xa.s8, bf0.s8, z, 0, 0, 0);
    f32x4 d1 = __builtin_amdgcn_mfma_f32_16x16x32_bf16(xa.s8, bf1.s8, z, 0, 0, 0);
#pragma unroll
    for (int r = 0; r < 4; ++r) {
      qbf[(quad * 4 + r) * 32 + lam] = f2bf(d0[r]);
      qbf[(quad * 4 + r) * 32 + 16 + lam] = f2bf(d1[r]);
    }
  }

  // ---- per-lane resident weights (all waves; needed for P2) ----
  f32x2 w00r2[4], w01r2[4], b0r2[4];
#pragma unroll
  for (int j = 0; j < 4; ++j) {
    int k = quad * 8 + 2 * j;
    w00r2[j] = (f32x2){w0[k], w0[k + 1]};
    w01r2[j] = (f32x2){w0[32 + k], w0[32 + k + 1]};
    b0r2[j]  = (f32x2){b0[k], b0[k + 1]};
  }
  short8 w1f0, w1f1;   // W1^T A-frags (m=n-out, k=c-in), two 16-row tiles
#pragma unroll
  for (int j = 0; j < 8; ++j) {
    int k = quad * 8 + j;
    w1f0[j] = (short)f2bf(w1[k * 32 + lam]);
    w1f1[j] = (short)f2bf(w1[k * 32 + 16 + lam]);
  }
  f32x4 zA, zB;       // b1 folded into C-init (n = quad*4+r / 16+quad*4+r)
  f32x2 w2A01, w2A23, w2B01, w2B23;
#pragma unroll
  for (int r = 0; r < 4; ++r) {
    zA[r] = b1[quad * 4 + r];
    zB[r] = b1[16 + quad * 4 + r];
  }
  w2A01 = (f32x2){w2[quad * 4], w2[quad * 4 + 1]};
  w2A23 = (f32x2){w2[quad * 4 + 2], w2[quad * 4 + 3]};
  w2B01 = (f32x2){w2[16 + quad * 4], w2[16 + quad * 4 + 1]};
  w2B23 = (f32x2){w2[16 + quad * 4 + 2], w2[16 + quad * 4 + 3]};
  // b2 dropped: scalar shift of all logits, softmax-invariant (exact).

  __syncthreads();   // B0: qbf + st ready

  // ---- P1: sim = q·kT (scaled), bk prefetched; wave 7 takes the jt=8 tile ----
  const float scale = 0.17677669529663687f;   // 32^-0.5
  {
    short8 aq = *(const short8*)(qbf + lam * 32 + quad * 8);
    f32x4 z = {0.f, 0.f, 0.f, 0.f};
    f32x4 acc = __builtin_amdgcn_mfma_f32_16x16x32_bf16(aq, bk0, z, 0, 0, 0);
#pragma unroll
    for (int r = 0; r < 4; ++r)
      Ls[(quad * 4 + r) * LSP + w * 16 + lam] = acc[r] * scale;
    if (w == 7) {
      f32x4 acc8 = __builtin_amdgcn_mfma_f32_16x16x32_bf16(aq, bk8, z, 0, 0, 0);
#pragma unroll
      for (int r = 0; r < 4; ++r)
        Ls[(quad * 4 + r) * LSP + 128 + lam] = acc8[r] * scale;
    }
  }

  // ---- P2-compute: CPB bias MLP -> bvs (no sim dependency, no barrier) ----
  const f32x2 zero2 = {0.f, 0.f};
  int wr = w & 3;
  int pbase = wr * 576;
  int sA = (w < 4) ? 0 : 4;
  int sB = (w < 4) ? 4 : 9;
#pragma unroll 1
  for (int s = sA; s < sB; ++s) {
    float bm[4];
#pragma unroll
    for (int mt = 0; mt < 4; ++mt) {
      int Pm = pbase + s * 64 + mt * 16 + lam;
      float s0 = st0f[Pm];                     // broadcast across quads
      int iim = Pm / 144;
      float s1 = st1f[Pm - iim * 144];
      f32x2 s0v = {s0, s0}, s1v = {s1, s1};
      union { uint u[4]; short8 s8; } cvt;
#pragma unroll
      for (int j = 0; j < 4; ++j) {
        f32x2 hv = __builtin_elementwise_max(
            __builtin_elementwise_fma(s0v, w00r2[j],
                __builtin_elementwise_fma(s1v, w01r2[j], b0r2[j])), zero2);
        cvt.u[j] = packbf(hv[1], hv[0]);
      }
      f32x4 dA = __builtin_amdgcn_mfma_f32_16x16x32_bf16(w1f0, cvt.s8, zA, 0, 0, 0);
      f32x4 dB = __builtin_amdgcn_mfma_f32_16x16x32_bf16(w1f1, cvt.s8, zB, 0, 0, 0);
      f32x2 a01 = __builtin_elementwise_max((f32x2){dA[0], dA[1]}, zero2);
      f32x2 a23 = __builtin_elementwise_max((f32x2){dA[2], dA[3]}, zero2);
      f32x2 c01 = __builtin_elementwise_max((f32x2){dB[0], dB[1]}, zero2);
      f32x2 c23 = __builtin_elementwise_max((f32x2){dB[2], dB[3]}, zero2);
      f32x2 av = __builtin_elementwise_fma(a01, w2A01,
                 __builtin_elementwise_fma(a23, w2A23,
                 __builtin_elementwise_fma(c01, w2B01,
                 __builtin_elementwise_fma(c23, w2B23, zero2))));
      float acc = av[0] + av[1];
      acc += __shfl_xor(acc, 16, 64);
      acc += __shfl_xor(acc, 32, 64);
      bm[mt] = acc;
    }
    float biasv = (quad == 0 ? bm[0] : quad == 1 ? bm[1] : quad == 2 ? bm[2] : bm[3]);
    bvs[(s - sA) * 512 + t] = biasv;           // per-thread slot
  }
  __syncthreads();   // B2: sim in Ls complete, bvs complete

  // ---- prefetch v-frags for P4 (waves 0,1); latency hides under add+P3 ----
  short8 vf[5];
  if (w < 2) {
    const ushort* vb = vtb + bg * 5120 + (w * 16 + lam) * 160;
#pragma unroll
    for (int kb = 0; kb < 5; ++kb)
      vf[kb] = *(const short8*)(vb + kb * 32 + quad * 8);
  }

  // ---- fused bias-add + P3 softmax (waves 0-3; no barrier between) ----
  // Wave w owns rows w*4..w*4+3: its own bvs half (s<4) + wave w+4's (s>=4).
  if (w < 4) {
#pragma unroll
    for (int s = 0; s < 9; ++s) {
      int P = s * 64 + lane;
      int ii = P / 144, jj = P - ii * 144;
      float bv = (s < 4) ? bvs[s * 512 + w * 64 + lane]
                         : bvs[(s - 4) * 512 + (w + 4) * 64 + lane];
      Ls[(w * 4 + ii) * LSP + jj] += bv;
    }
    int row = w * 4 + quad;
    float* Lp = Ls + row * LSP;
    float lv[9];
#pragma unroll
    for (int k = 0; k < 9; ++k) lv[k] = Lp[lam + 16 * k];
    float m = lv[0];
#pragma unroll
    for (int k = 1; k < 9; ++k) m = fmaxf(m, lv[k]);
#pragma unroll
    for (int k = 8; k >= 1; k >>= 1) m = fmaxf(m, __shfl_xor(m, k, 64));
    float e[9], sum = 0.f;
#pragma unroll
    for (int k = 0; k < 9; ++k) { e[k] = __expf(lv[k] - m); sum += e[k]; }
#pragma unroll
    for (int k = 8; k >= 1; k >>= 1) sum += __shfl_xor(sum, k, 64);
    float inv = 1.f / sum;
    ushort* pb = (ushort*)(Lp + 64);
#pragma unroll
    for (int k = 0; k < 9; ++k) pb[lam + 16 * k] = f2bf(e[k] * inv);
    pb[144 + lam] = 0;   // K-pad for P4
  }
  __syncthreads();   // B4

  // ---- P4: O = P·v (K=160, zero-padded); waves 0,1 take the 2 col-halves ----
  if (w < 2) {
    f32x4 o = {0.f, 0.f, 0.f, 0.f};
    const ushort* pb = (const ushort*)(Ls + lam * LSP + 64);
#pragma unroll
    for (int kb = 0; kb < 5; ++kb) {
      short8 ap = *(const short8*)(pb + kb * 32 + quad * 8);
      o = __builtin_amdgcn_mfma_f32_16x16x32_bf16(ap, vf[kb], o, 0, 0, 0);
    }
#pragma unroll
    for (int r = 0; r < 4; ++r) {
      int ig = i0 + quad * 4 + r;
      outh[((long)b * HWHW + ig) * 128 + g * 32 + w * 16 + lam] = f2bf(o[r]);
    }
  }
}

// grid (144 hw-chunks, 2 b, 2 oc-halves), 256 thr = 4 waves; wave owns 16 oc.
// MFMA out-proj, zero LDS: A-frags straight from bf16 outh; B-frags from fp32
// wo with inline v_perm pack.
__global__ __launch_bounds__(256) void out_kernel(
    const ushort* __restrict__ outh, const float* __restrict__ wo,
    const float* __restrict__ bo, const float* __restrict__ x,
    const float* __restrict__ gamma, float* __restrict__ out) {
  int b = blockIdx.y;
  int hw0 = blockIdx.x * 16;
  int oc0 = blockIdx.z * 64;
  int t = threadIdx.x;
  int w = t >> 6, lane = t & 63, lam = lane & 15, quad = lane >> 4;
  const ushort* abase = outh + ((long)b * HWHW + hw0 + lam) * 128 + quad * 8;
  const float* wb0 = wo + (oc0 + w * 16 + lam) * 128 + quad * 8;
  f32x4 acc0 = {0.f, 0.f, 0.f, 0.f};
#pragma unroll
  for (int ks = 0; ks < 4; ++ks) {
    short8 a = *(const short8*)(abase + ks * 32);
    float4 wa = *(const float4*)(wb0 + ks * 32);
    float4 wb = *(const float4*)(wb0 + ks * 32 + 4);
    union { uint u[4]; short8 s8; } p0;
    p0.u[0] = packbf(wa.y, wa.x); p0.u[1] = packbf(wa.w, wa.z);
    p0.u[2] = packbf(wb.y, wb.x); p0.u[3] = packbf(wb.w, wb.z);
    acc0 = __builtin_amdgcn_mfma_f32_16x16x32_bf16(a, p0.s8, acc0, 0, 0, 0);
  }
  float gm = gamma[0];
  float* out0 = out;
  float* out1 = out + 2 * 128 * HWHW;
  {
    int oc = oc0 + w * 16 + lam;
    float bv = bo[oc];
    long base = ((long)(b * 128 + oc)) * HWHW + hw0 + quad * 4;
    float4 xv = *(const float4*)(x + base);
    float4 a1, a0;
    a1.x = acc0[0] + bv; a1.y = acc0[1] + bv; a1.z = acc0[2] + bv; a1.w = acc0[3] + bv;
    a0.x = fmaf(gm, a1.x, xv.x); a0.y = fmaf(gm, a1.y, xv.y);
    a0.z = fmaf(gm, a1.z, xv.z); a0.w = fmaf(gm, a1.w, xv.w);
    *(float4*)(out1 + base) = a1;
    *(float4*)(out0 + base) = a0;
  }
}

extern "C" void kernel_launch(void* const* d_in, const int* in_sizes, int n_in,
                              void* d_out, int out_size, void* d_ws, size_t ws_size,
                              hipStream_t stream) {
  const float* x     = (const float*)d_in[0];
  const float* gamma = (const float*)d_in[1];
  const float* wq    = (const float*)d_in[2];
  const float* wk    = (const float*)d_in[3];
  const float* wv    = (const float*)d_in[4];
  const float* wo    = (const float*)d_in[5];
  const float* bo    = (const float*)d_in[6];
  const float* wdw   = (const float*)d_in[7];
  const float* bdw   = (const float*)d_in[8];
  const float* wproj = (const float*)d_in[9];
  const float* cw0   = (const float*)d_in[10];
  const float* cb0   = (const float*)d_in[11];
  const float* cw1   = (const float*)d_in[12];
  const float* cb1   = (const float*)d_in[13];
  const float* cw2   = (const float*)d_in[14];
  char* wsb = (char*)d_ws;
  ushort* ktb = (ushort*)(wsb + 9216);
  ushort* vtb = (ushort*)(wsb + 82944);
  ushort* outh = (ushort*)(wsb + 164864);
  float* S0g  = (float*)(wsb + 1344512);
  float* S1g  = (float*)(wsb + 1565696);
  float* out  = (float*)d_out;

  offset_kv_kernel<<<dim3(12, 8), 384, 0, stream>>>(x, wq, wdw, bdw, wproj, wk, wv,
                                                    ktb, vtb, S0g, S1g);
  attn_fused_kernel<<<dim3(144, 8), 512, 0, stream>>>(x, wq, ktb, vtb, S0g, S1g,
                                                      cw0, cb0, cw1, cb1, cw2, outh);
  out_kernel<<<dim3(144, 2, 2), 256, 0, stream>>>(outh, wo, bo, x, gamma, out);
}